// Round 1
// baseline (221.134 us; speedup 1.0000x reference)
//
#include <hip/hip_runtime.h>
#include <math.h>

#define N_ATOMS 512
#define F_DIM   128
#define K_RBF   301
#define NLAYER  3
#define GAMMA_C 10.0f
#define LOG2_C  0.6931471805599453f

// Filter lookup table: w_l(d) sampled at step TAB_H over [0, 17.5975]
#define TAB_H    0.0025f
#define TAB_INVH 400.0f
#define TAB_ROWS 7040
#define RPB      8      // table rows built per block

__device__ __forceinline__ float ssp(float x) {
    // shifted softplus: softplus(x) - log(2), numerically stable
    float ax = fabsf(x);
    return fmaxf(x, 0.0f) + log1pf(expf(-ax)) - LOG2_C;
}

// ---------------------------------------------------------------------------
// d[i,j] = |r_i - r_j|  and  h = emb[x]
// grid: N_ATOMS blocks x 256 threads
__global__ void prep_kernel(const int* __restrict__ x, const float* __restrict__ r,
                            const float* __restrict__ emb,
                            float* __restrict__ dmat, float* __restrict__ h) {
    int i = blockIdx.x;
    int t = threadIdx.x;
    float rx = r[i * 3 + 0], ry = r[i * 3 + 1], rz = r[i * 3 + 2];
    if (t < F_DIM) {
        h[i * F_DIM + t] = emb[x[i] * F_DIM + t];
    }
    for (int j = t; j < N_ATOMS; j += 256) {
        float dx = rx - r[j * 3 + 0];
        float dy = ry - r[j * 3 + 1];
        float dz = rz - r[j * 3 + 2];
        float d2 = dx * dx + dy * dy + dz * dz;
        dmat[i * N_ATOMS + j] = sqrtf(d2);  // sqrt(0)=0 on diagonal, matches ref mask
    }
}

// ---------------------------------------------------------------------------
// Build tables: tab[l, row, f] = ssp(ssp(e(d_row)@W1_l + b1_l)@W2_l + b2_l)
// grid: (TAB_ROWS/RPB, 3) blocks x 128 threads
__global__ void build_tables(const float* __restrict__ cf_W1, const float* __restrict__ cf_b1,
                             const float* __restrict__ cf_W2, const float* __restrict__ cf_b2,
                             float* __restrict__ tab) {
    int row0 = blockIdx.x * RPB;
    int l    = blockIdx.y;
    int f    = threadIdx.x;

    float dlo = row0 * TAB_H;
    float dhi = (row0 + RPB - 1) * TAB_H;
    // active Gaussian window: exp(-10*1.45^2) ~ 7.6e-10, negligible truncation
    int k0 = ::max(0, (int)ceilf((dlo - 1.45f) * 10.0f));
    int k1 = ::min(K_RBF - 1, (int)floorf((dhi + 1.45f) * 10.0f));
    int kw = k1 - k0 + 1;   // <= ~30

    __shared__ float e_s[RPB][40];
    __shared__ float w1_s[RPB][F_DIM];

    for (int idx = f; idx < RPB * kw; idx += F_DIM) {
        int rr = idx / kw, kk = idx % kw;
        float dv = (row0 + rr) * TAB_H;
        float tt = dv - 0.1f * (float)(k0 + kk);
        e_s[rr][kk] = expf(-GAMMA_C * tt * tt);
    }
    __syncthreads();

    const float* W1 = cf_W1 + l * K_RBF * F_DIM;
    float b1v = cf_b1[l * F_DIM + f];
    float acc[RPB];
#pragma unroll
    for (int rr = 0; rr < RPB; ++rr) acc[rr] = b1v;
    for (int kk = 0; kk < kw; ++kk) {
        float w1v = W1[(k0 + kk) * F_DIM + f];
#pragma unroll
        for (int rr = 0; rr < RPB; ++rr) acc[rr] = fmaf(e_s[rr][kk], w1v, acc[rr]);
    }
#pragma unroll
    for (int rr = 0; rr < RPB; ++rr) w1_s[rr][f] = ssp(acc[rr]);
    __syncthreads();

    const float* W2 = cf_W2 + l * F_DIM * F_DIM;
    float b2v = cf_b2[l * F_DIM + f];
    float acc2[RPB];
#pragma unroll
    for (int rr = 0; rr < RPB; ++rr) acc2[rr] = b2v;
    for (int g = 0; g < F_DIM; ++g) {
        float w2v = W2[g * F_DIM + f];
#pragma unroll
        for (int rr = 0; rr < RPB; ++rr) acc2[rr] = fmaf(w1_s[rr][g], w2v, acc2[rr]);
    }
#pragma unroll
    for (int rr = 0; rr < RPB; ++rr)
        tab[(l * TAB_ROWS + row0 + rr) * F_DIM + f] = ssp(acc2[rr]);
}

// ---------------------------------------------------------------------------
// o = h @ aw_W[l] + aw_b[l]     grid: N_ATOMS blocks x 128 threads
__global__ void atomwise_kernel(const float* __restrict__ h, const float* __restrict__ aw_W,
                                const float* __restrict__ aw_b, float* __restrict__ o, int l) {
    int i = blockIdx.x, f = threadIdx.x;
    __shared__ float hs[F_DIM];
    hs[f] = h[i * F_DIM + f];
    __syncthreads();
    const float* W = aw_W + l * F_DIM * F_DIM;
    float acc = aw_b[l * F_DIM + f];
    for (int g = 0; g < F_DIM; ++g) acc = fmaf(hs[g], W[g * F_DIM + f], acc);
    o[i * F_DIM + f] = acc;
}

// ---------------------------------------------------------------------------
// c[i,f] = sum_j lerp(tab_l, d[i,j])[f] * o[j,f]
// grid: N_ATOMS blocks x 512 threads (thread t: f = t&127, j-quarter = t>>7)
__global__ void __launch_bounds__(512)
conv_kernel(const float* __restrict__ dmat, const float* __restrict__ o,
            const float* __restrict__ tab, float* __restrict__ c, int l) {
    int i  = blockIdx.x;
    int t  = threadIdx.x;
    int f  = t & (F_DIM - 1);
    int jc = t >> 7;            // 0..3

    __shared__ float ds[N_ATOMS];
    __shared__ float red[4][F_DIM];

    for (int j = t; j < N_ATOMS; j += 512) ds[j] = dmat[i * N_ATOMS + j];
    __syncthreads();

    const float* T = tab + l * TAB_ROWS * F_DIM;
    float acc = 0.0f;
#pragma unroll 4
    for (int jj = 0; jj < N_ATOMS / 4; ++jj) {
        int j = jc * (N_ATOMS / 4) + jj;
        float dv = ds[j];                       // LDS broadcast
        float xb = dv * TAB_INVH;
        int   b  = ::min((int)xb, TAB_ROWS - 2);
        float fr = xb - (float)b;
        const float* rowp = T + b * F_DIM + f;
        float t0 = rowp[0];
        float t1 = rowp[F_DIM];
        float w  = fmaf(fr, t1 - t0, t0);       // linear interp
        acc = fmaf(w, o[j * F_DIM + f], acc);
    }
    red[jc][f] = acc;
    __syncthreads();
    if (jc == 0) {
        c[i * F_DIM + f] = red[0][f] + red[1][f] + red[2][f] + red[3][f];
    }
}

// ---------------------------------------------------------------------------
// h += ssp(c @ n_W1 + n_b1) @ n_W2 + n_b2    grid: N_ATOMS blocks x 128 threads
__global__ void node_kernel(const float* __restrict__ c, const float* __restrict__ n_W1,
                            const float* __restrict__ n_b1, const float* __restrict__ n_W2,
                            const float* __restrict__ n_b2, float* __restrict__ h, int l) {
    int i = blockIdx.x, f = threadIdx.x;
    __shared__ float cs[F_DIM];
    __shared__ float t1s[F_DIM];
    cs[f] = c[i * F_DIM + f];
    __syncthreads();
    const float* W1 = n_W1 + l * F_DIM * F_DIM;
    float a = n_b1[l * F_DIM + f];
    for (int g = 0; g < F_DIM; ++g) a = fmaf(cs[g], W1[g * F_DIM + f], a);
    t1s[f] = ssp(a);
    __syncthreads();
    const float* W2 = n_W2 + l * F_DIM * F_DIM;
    float a2 = n_b2[l * F_DIM + f];
    for (int g = 0; g < F_DIM; ++g) a2 = fmaf(t1s[g], W2[g * F_DIM + f], a2);
    h[i * F_DIM + f] += a2;
}

// ---------------------------------------------------------------------------
// out[i] = ssp(h[i] @ out_W1 + out_b1) @ out_W2 + out_b2
// grid: N_ATOMS blocks x 64 threads
__global__ void head_kernel(const float* __restrict__ h, const float* __restrict__ W1,
                            const float* __restrict__ b1, const float* __restrict__ W2,
                            const float* __restrict__ b2, float* __restrict__ out) {
    int i = blockIdx.x, t = threadIdx.x;
    __shared__ float hs[F_DIM];
    hs[t]      = h[i * F_DIM + t];
    hs[t + 64] = h[i * F_DIM + t + 64];
    __syncthreads();
    float val = 0.0f;
    if (t < 32) {
        float a = b1[t];
        for (int g = 0; g < F_DIM; ++g) a = fmaf(hs[g], W1[g * 32 + t], a);
        val = ssp(a) * W2[t];
    }
#pragma unroll
    for (int off = 32; off > 0; off >>= 1) val += __shfl_xor(val, off, 64);
    if (t == 0) out[i] = val + b2[0];
}

// ---------------------------------------------------------------------------
extern "C" void kernel_launch(void* const* d_in, const int* in_sizes, int n_in,
                              void* d_out, int out_size, void* d_ws, size_t ws_size,
                              hipStream_t stream) {
    const int*   x     = (const int*)  d_in[0];
    const float* r     = (const float*)d_in[1];
    const float* emb   = (const float*)d_in[2];
    const float* aw_W  = (const float*)d_in[3];
    const float* aw_b  = (const float*)d_in[4];
    const float* cf_W1 = (const float*)d_in[5];
    const float* cf_b1 = (const float*)d_in[6];
    const float* cf_W2 = (const float*)d_in[7];
    const float* cf_b2 = (const float*)d_in[8];
    const float* n_W1  = (const float*)d_in[9];
    const float* n_b1  = (const float*)d_in[10];
    const float* n_W2  = (const float*)d_in[11];
    const float* n_b2  = (const float*)d_in[12];
    const float* oW1   = (const float*)d_in[13];
    const float* ob1   = (const float*)d_in[14];
    const float* oW2   = (const float*)d_in[15];
    const float* ob2   = (const float*)d_in[16];
    float* out = (float*)d_out;

    char* ws = (char*)d_ws;
    float* dmat = (float*)ws; ws += (size_t)N_ATOMS * N_ATOMS * 4;   // 1 MB
    float* h    = (float*)ws; ws += (size_t)N_ATOMS * F_DIM * 4;     // 256 KB
    float* o    = (float*)ws; ws += (size_t)N_ATOMS * F_DIM * 4;     // 256 KB
    float* c    = (float*)ws; ws += (size_t)N_ATOMS * F_DIM * 4;     // 256 KB
    float* tab  = (float*)ws;                                        // 3 * 3.6 MB

    prep_kernel<<<N_ATOMS, 256, 0, stream>>>(x, r, emb, dmat, h);
    build_tables<<<dim3(TAB_ROWS / RPB, NLAYER), 128, 0, stream>>>(cf_W1, cf_b1, cf_W2, cf_b2, tab);
    for (int l = 0; l < NLAYER; ++l) {
        atomwise_kernel<<<N_ATOMS, 128, 0, stream>>>(h, aw_W, aw_b, o, l);
        conv_kernel<<<N_ATOMS, 512, 0, stream>>>(dmat, o, tab, c, l);
        node_kernel<<<N_ATOMS, 128, 0, stream>>>(c, n_W1, n_b1, n_W2, n_b2, h, l);
    }
    head_kernel<<<N_ATOMS, 64, 0, stream>>>(h, oW1, ob1, oW2, ob2, out);
}

// Round 2
// 191.400 us; speedup vs baseline: 1.1553x; 1.1553x over previous
//
#include <hip/hip_runtime.h>
#include <hip/hip_fp16.h>
#include <math.h>

#define N_ATOMS 512
#define F_DIM   128
#define K_RBF   301
#define NLAYER  3
#define GAMMA_C 10.0f
#define LOG2_C  0.6931471805599453f

// Filter lookup table: w_l(d) sampled at step TAB_H; max d = 10*sqrt(3) = 17.32
#define TAB_H    0.01f
#define TAB_INVH 100.0f
#define TAB_ROWS 1768      // 221 * 8, covers up to 17.67
#define RPB      8         // table rows built per block

__device__ __forceinline__ float ssp(float x) {
    // shifted softplus: softplus(x) - log(2), numerically stable
    float ax = fabsf(x);
    return fmaxf(x, 0.0f) + log1pf(expf(-ax)) - LOG2_C;
}

// ---------------------------------------------------------------------------
// d[i,j] = |r_i - r_j|, h = emb[x], o0 = h @ aw_W[0] + aw_b[0]
// grid: N_ATOMS blocks x 256 threads
__global__ void prep_kernel(const int* __restrict__ x, const float* __restrict__ r,
                            const float* __restrict__ emb,
                            const float* __restrict__ aw_W, const float* __restrict__ aw_b,
                            float* __restrict__ dmat, float* __restrict__ h,
                            float* __restrict__ o) {
    int i = blockIdx.x;
    int t = threadIdx.x;
    __shared__ float hs[F_DIM];
    float rx = r[i * 3 + 0], ry = r[i * 3 + 1], rz = r[i * 3 + 2];
    if (t < F_DIM) {
        float hv = emb[x[i] * F_DIM + t];
        h[i * F_DIM + t] = hv;
        hs[t] = hv;
    }
    for (int j = t; j < N_ATOMS; j += 256) {
        float dx = rx - r[j * 3 + 0];
        float dy = ry - r[j * 3 + 1];
        float dz = rz - r[j * 3 + 2];
        dmat[i * N_ATOMS + j] = sqrtf(dx * dx + dy * dy + dz * dz);
    }
    __syncthreads();
    if (t < F_DIM) {
        float acc = aw_b[t];
        for (int g = 0; g < F_DIM; ++g) acc = fmaf(hs[g], aw_W[g * F_DIM + t], acc);
        o[i * F_DIM + t] = acc;
    }
}

// ---------------------------------------------------------------------------
// Build tables: tab[l, row, f] = ssp(ssp(e(d_row)@W1_l + b1_l)@W2_l + b2_l)
// grid: (TAB_ROWS/RPB, 3) blocks x 128 threads
__global__ void build_tables(const float* __restrict__ cf_W1, const float* __restrict__ cf_b1,
                             const float* __restrict__ cf_W2, const float* __restrict__ cf_b2,
                             float* __restrict__ tab) {
    int row0 = blockIdx.x * RPB;
    int l    = blockIdx.y;
    int f    = threadIdx.x;

    float dlo = row0 * TAB_H;
    float dhi = (row0 + RPB - 1) * TAB_H;
    // active Gaussian window: exp(-10*1.45^2) ~ 7.6e-10, negligible truncation
    int k0 = ::max(0, (int)ceilf((dlo - 1.45f) * 10.0f));
    int k1 = ::min(K_RBF - 1, (int)floorf((dhi + 1.45f) * 10.0f));
    int kw = k1 - k0 + 1;   // <= ~30

    __shared__ float e_s[RPB][40];
    __shared__ float w1_s[F_DIM][RPB];   // transposed: float4-able broadcast reads

    for (int idx = f; idx < RPB * kw; idx += F_DIM) {
        int rr = idx / kw, kk = idx % kw;
        float dv = (row0 + rr) * TAB_H;
        float tt = dv - 0.1f * (float)(k0 + kk);
        e_s[rr][kk] = expf(-GAMMA_C * tt * tt);
    }
    __syncthreads();

    const float* W1 = cf_W1 + l * K_RBF * F_DIM;
    float b1v = cf_b1[l * F_DIM + f];
    float acc[RPB];
#pragma unroll
    for (int rr = 0; rr < RPB; ++rr) acc[rr] = b1v;
    for (int kk = 0; kk < kw; ++kk) {
        float w1v = W1[(k0 + kk) * F_DIM + f];
#pragma unroll
        for (int rr = 0; rr < RPB; ++rr) acc[rr] = fmaf(e_s[rr][kk], w1v, acc[rr]);
    }
    {
        float4 s0, s1;
        s0.x = ssp(acc[0]); s0.y = ssp(acc[1]); s0.z = ssp(acc[2]); s0.w = ssp(acc[3]);
        s1.x = ssp(acc[4]); s1.y = ssp(acc[5]); s1.z = ssp(acc[6]); s1.w = ssp(acc[7]);
        *(float4*)&w1_s[f][0] = s0;
        *(float4*)&w1_s[f][4] = s1;
    }
    __syncthreads();

    const float* W2 = cf_W2 + l * F_DIM * F_DIM;
    float b2v = cf_b2[l * F_DIM + f];
    float acc2[RPB];
#pragma unroll
    for (int rr = 0; rr < RPB; ++rr) acc2[rr] = b2v;
    for (int g = 0; g < F_DIM; ++g) {
        float w2v = W2[g * F_DIM + f];
        float4 wa = *(const float4*)&w1_s[g][0];   // broadcast b128
        float4 wb = *(const float4*)&w1_s[g][4];
        acc2[0] = fmaf(wa.x, w2v, acc2[0]);
        acc2[1] = fmaf(wa.y, w2v, acc2[1]);
        acc2[2] = fmaf(wa.z, w2v, acc2[2]);
        acc2[3] = fmaf(wa.w, w2v, acc2[3]);
        acc2[4] = fmaf(wb.x, w2v, acc2[4]);
        acc2[5] = fmaf(wb.y, w2v, acc2[5]);
        acc2[6] = fmaf(wb.z, w2v, acc2[6]);
        acc2[7] = fmaf(wb.w, w2v, acc2[7]);
    }
#pragma unroll
    for (int rr = 0; rr < RPB; ++rr)
        tab[(l * TAB_ROWS + row0 + rr) * F_DIM + f] = ssp(acc2[rr]);
}

// ---------------------------------------------------------------------------
// ptab[l,row,f] = half2(t0, t1-t0) — one 4B load per interp in conv
__global__ void pack_tables(const float* __restrict__ tab, __half2* __restrict__ ptab) {
    int idx = blockIdx.x * 256 + threadIdx.x;
    int total = NLAYER * TAB_ROWS * F_DIM;
    if (idx >= total) return;
    int row = (idx / F_DIM) % TAB_ROWS;
    float t0 = tab[idx];
    float t1 = (row < TAB_ROWS - 1) ? tab[idx + F_DIM] : t0;
    ptab[idx] = __halves2half2(__float2half(t0), __float2half(t1 - t0));
}

// ---------------------------------------------------------------------------
// c[i,f] = sum_j lerp(ptab_l, d[i,j])[f] * o[j,f]
// grid: N_ATOMS blocks x 512 threads (thread t: f = t&127, j-quarter = t>>7)
__global__ void __launch_bounds__(512)
conv_kernel(const float* __restrict__ dmat, const float* __restrict__ o,
            const __half2* __restrict__ ptab, float* __restrict__ c, int l) {
    int i  = blockIdx.x;
    int t  = threadIdx.x;
    int f  = t & (F_DIM - 1);
    int jc = t >> 7;            // 0..3

    __shared__ float ds[N_ATOMS];
    __shared__ float red[4][F_DIM];

    for (int j = t; j < N_ATOMS; j += 512) ds[j] = dmat[i * N_ATOMS + j];
    __syncthreads();

    const __half2* T = ptab + l * TAB_ROWS * F_DIM;
    float acc = 0.0f;
#pragma unroll 4
    for (int jj = 0; jj < N_ATOMS / 4; ++jj) {
        int j = jc * (N_ATOMS / 4) + jj;
        float dv = ds[j];                       // LDS broadcast
        float xb = dv * TAB_INVH;
        int   b  = ::min((int)xb, TAB_ROWS - 2);
        float fr = xb - (float)b;
        __half2 tv = T[b * F_DIM + f];          // (t0, t1-t0) in one dword
        float t0 = __half2float(__low2half(tv));
        float dt = __half2float(__high2half(tv));
        float w  = fmaf(fr, dt, t0);            // linear interp
        acc = fmaf(w, o[j * F_DIM + f], acc);
    }
    red[jc][f] = acc;
    __syncthreads();
    if (jc == 0) {
        c[i * F_DIM + f] = red[0][f] + red[1][f] + red[2][f] + red[3][f];
    }
}

// ---------------------------------------------------------------------------
// h += ssp(c @ n_W1 + n_b1) @ n_W2 + n_b2; then either o = h @ aw_W[l+1] + b
// (l<2) or the output head (l==2).  grid: N_ATOMS blocks x 128 threads
__global__ void node_fused(const float* __restrict__ c, const float* __restrict__ n_W1,
                           const float* __restrict__ n_b1, const float* __restrict__ n_W2,
                           const float* __restrict__ n_b2, float* __restrict__ h,
                           const float* __restrict__ aw_W, const float* __restrict__ aw_b,
                           float* __restrict__ o,
                           const float* __restrict__ oW1, const float* __restrict__ ob1,
                           const float* __restrict__ oW2, const float* __restrict__ ob2,
                           float* __restrict__ out, int l) {
    int i = blockIdx.x, f = threadIdx.x;
    __shared__ float cs[F_DIM];
    __shared__ float t1s[F_DIM];
    __shared__ float hs[F_DIM];
    cs[f] = c[i * F_DIM + f];
    __syncthreads();
    const float* W1 = n_W1 + l * F_DIM * F_DIM;
    float a = n_b1[l * F_DIM + f];
    for (int g = 0; g < F_DIM; ++g) a = fmaf(cs[g], W1[g * F_DIM + f], a);
    t1s[f] = ssp(a);
    __syncthreads();
    const float* W2 = n_W2 + l * F_DIM * F_DIM;
    float a2 = n_b2[l * F_DIM + f];
    for (int g = 0; g < F_DIM; ++g) a2 = fmaf(t1s[g], W2[g * F_DIM + f], a2);
    float hv = h[i * F_DIM + f] + a2;
    h[i * F_DIM + f] = hv;
    hs[f] = hv;
    __syncthreads();

    if (l < NLAYER - 1) {
        // next layer's atom-wise linear
        const float* W = aw_W + (l + 1) * F_DIM * F_DIM;
        float acc = aw_b[(l + 1) * F_DIM + f];
        for (int g = 0; g < F_DIM; ++g) acc = fmaf(hs[g], W[g * F_DIM + f], acc);
        o[i * F_DIM + f] = acc;
    } else {
        // output head: out[i] = ssp(h @ oW1 + ob1) @ oW2 + ob2
        float val = 0.0f;
        if (f < 32) {
            float ah = ob1[f];
            for (int g = 0; g < F_DIM; ++g) ah = fmaf(hs[g], oW1[g * 32 + f], ah);
            val = ssp(ah) * oW2[f];
        }
#pragma unroll
        for (int off = 16; off > 0; off >>= 1) val += __shfl_xor(val, off, 64);
        if (f == 0) out[i] = val + ob2[0];
    }
}

// ---------------------------------------------------------------------------
extern "C" void kernel_launch(void* const* d_in, const int* in_sizes, int n_in,
                              void* d_out, int out_size, void* d_ws, size_t ws_size,
                              hipStream_t stream) {
    const int*   x     = (const int*)  d_in[0];
    const float* r     = (const float*)d_in[1];
    const float* emb   = (const float*)d_in[2];
    const float* aw_W  = (const float*)d_in[3];
    const float* aw_b  = (const float*)d_in[4];
    const float* cf_W1 = (const float*)d_in[5];
    const float* cf_b1 = (const float*)d_in[6];
    const float* cf_W2 = (const float*)d_in[7];
    const float* cf_b2 = (const float*)d_in[8];
    const float* n_W1  = (const float*)d_in[9];
    const float* n_b1  = (const float*)d_in[10];
    const float* n_W2  = (const float*)d_in[11];
    const float* n_b2  = (const float*)d_in[12];
    const float* oW1   = (const float*)d_in[13];
    const float* ob1   = (const float*)d_in[14];
    const float* oW2   = (const float*)d_in[15];
    const float* ob2   = (const float*)d_in[16];
    float* out = (float*)d_out;

    char* ws = (char*)d_ws;
    float*   dmat = (float*)ws;   ws += (size_t)N_ATOMS * N_ATOMS * 4;        // 1 MB
    float*   h    = (float*)ws;   ws += (size_t)N_ATOMS * F_DIM * 4;          // 256 KB
    float*   o    = (float*)ws;   ws += (size_t)N_ATOMS * F_DIM * 4;          // 256 KB
    float*   c    = (float*)ws;   ws += (size_t)N_ATOMS * F_DIM * 4;          // 256 KB
    float*   tab  = (float*)ws;   ws += (size_t)NLAYER * TAB_ROWS * F_DIM * 4; // 2.7 MB
    __half2* ptab = (__half2*)ws;                                             // 1.36 MB

    prep_kernel<<<N_ATOMS, 256, 0, stream>>>(x, r, emb, aw_W, aw_b, dmat, h, o);
    build_tables<<<dim3(TAB_ROWS / RPB, NLAYER), 128, 0, stream>>>(cf_W1, cf_b1, cf_W2, cf_b2, tab);
    {
        int total = NLAYER * TAB_ROWS * F_DIM;
        pack_tables<<<(total + 255) / 256, 256, 0, stream>>>(tab, ptab);
    }
    for (int l = 0; l < NLAYER; ++l) {
        conv_kernel<<<N_ATOMS, 512, 0, stream>>>(dmat, o, ptab, c, l);
        node_fused<<<N_ATOMS, 128, 0, stream>>>(c, n_W1, n_b1, n_W2, n_b2, h,
                                                aw_W, aw_b, o, oW1, ob1, oW2, ob2, out, l);
    }
}

// Round 3
// 175.154 us; speedup vs baseline: 1.2625x; 1.0928x over previous
//
#include <hip/hip_runtime.h>
#include <hip/hip_fp16.h>
#include <math.h>

#define N_ATOMS 512
#define F_DIM   128
#define K_RBF   301
#define NLAYER  3
#define GAMMA_C 10.0f
#define LOG2_C  0.6931471805599453f

// Filter lookup table: w_l(d) sampled at step TAB_H; max d = 10*sqrt(3) = 17.32
#define TAB_H     0.01f
#define TAB_INVH  100.0f
#define TAB_ROWS  1768          // 221 * 8, covers up to 17.67
#define RPB       8             // table rows emitted per block (computes RPB+1)
#define ROW_BYTES 512           // 64 f-pairs * 8 B (uint2 per pair)

__device__ __forceinline__ float ssp(float x) {
    float ax = fabsf(x);
    return fmaxf(x, 0.0f) + log1pf(expf(-ax)) - LOG2_C;
}
__device__ __forceinline__ __half2 u2h2(unsigned u) {
    union { unsigned u; __half2 h; } c; c.u = u; return c.h;
}
__device__ __forceinline__ unsigned h22u(__half2 h) {
    union { unsigned u; __half2 h; } c; c.h = h; return c.u;
}

// ---------------------------------------------------------------------------
// dpk[i,j] = (table row byte offset, fr as half2) ; h = emb[x] ;
// opk0 = half2-packed (h @ aw_W[0] + aw_b[0]).   grid: N_ATOMS x 256
__global__ void prep_kernel(const int* __restrict__ x, const float* __restrict__ r,
                            const float* __restrict__ emb,
                            const float* __restrict__ aw_W, const float* __restrict__ aw_b,
                            uint2* __restrict__ dpk, float* __restrict__ h,
                            unsigned* __restrict__ opk) {
    int i = blockIdx.x;
    int t = threadIdx.x;
    __shared__ float hs[F_DIM];
    __shared__ float os[F_DIM];
    float rx = r[i * 3 + 0], ry = r[i * 3 + 1], rz = r[i * 3 + 2];
    if (t < F_DIM) {
        float hv = emb[x[i] * F_DIM + t];
        h[i * F_DIM + t] = hv;
        hs[t] = hv;
    }
    for (int j = t; j < N_ATOMS; j += 256) {
        float dx = rx - r[j * 3 + 0];
        float dy = ry - r[j * 3 + 1];
        float dz = rz - r[j * 3 + 2];
        float d  = sqrtf(dx * dx + dy * dy + dz * dz);
        float xb = d * TAB_INVH;
        int   b  = ::min((int)xb, TAB_ROWS - 2);
        float fr = xb - (float)b;
        __half fh = __float2half(fr);
        dpk[i * N_ATOMS + j] = make_uint2((unsigned)b * ROW_BYTES,
                                          h22u(__halves2half2(fh, fh)));
    }
    __syncthreads();
    if (t < F_DIM) {
        float acc = aw_b[t];
        for (int g = 0; g < F_DIM; ++g) acc = fmaf(hs[g], aw_W[g * F_DIM + t], acc);
        os[t] = acc;
    }
    __syncthreads();
    if (t < F_DIM / 2)
        opk[i * 64 + t] = h22u(__halves2half2(__float2half(os[2 * t]),
                                              __float2half(os[2 * t + 1])));
}

// ---------------------------------------------------------------------------
// Build packed tables directly: ptab[l,row,pair] = uint2{half2(t0),half2(t1-t0)}
// Each block computes RPB+1 = 9 rows, emits RPB.  grid: (221, 3) x 128
__global__ void build_tables(const float* __restrict__ cf_W1, const float* __restrict__ cf_b1,
                             const float* __restrict__ cf_W2, const float* __restrict__ cf_b2,
                             uint2* __restrict__ ptab) {
    int row0 = blockIdx.x * RPB;
    int l    = blockIdx.y;
    int f    = threadIdx.x;

    float dlo = row0 * TAB_H;
    float dhi = (row0 + RPB) * TAB_H;
    // Gaussian window: exp(-10*1.45^2) ~ 7.6e-10 truncation
    int k0 = ::max(0, (int)ceilf((dlo - 1.45f) * 10.0f));
    int k1 = ::min(K_RBF - 1, (int)floorf((dhi + 1.45f) * 10.0f));
    int kw = k1 - k0 + 1;   // <= ~31

    __shared__ float e_s[RPB + 1][34];
    __shared__ float w1_s[F_DIM][12];        // 9 used, padded
    __shared__ float outs[RPB + 1][F_DIM];

    for (int idx = f; idx < (RPB + 1) * kw; idx += F_DIM) {
        int rr = idx / kw, kk = idx % kw;
        float dv = (row0 + rr) * TAB_H;
        float tt = dv - 0.1f * (float)(k0 + kk);
        e_s[rr][kk] = expf(-GAMMA_C * tt * tt);
    }
    __syncthreads();

    const float* W1 = cf_W1 + l * K_RBF * F_DIM;
    float b1v = cf_b1[l * F_DIM + f];
    float acc[RPB + 1];
#pragma unroll
    for (int rr = 0; rr <= RPB; ++rr) acc[rr] = b1v;
    for (int kk = 0; kk < kw; ++kk) {
        float w1v = W1[(k0 + kk) * F_DIM + f];
#pragma unroll
        for (int rr = 0; rr <= RPB; ++rr) acc[rr] = fmaf(e_s[rr][kk], w1v, acc[rr]);
    }
#pragma unroll
    for (int rr = 0; rr <= RPB; ++rr) w1_s[f][rr] = ssp(acc[rr]);
    __syncthreads();

    const float* W2 = cf_W2 + l * F_DIM * F_DIM;
    float b2v = cf_b2[l * F_DIM + f];
    float acc2[RPB + 1];
#pragma unroll
    for (int rr = 0; rr <= RPB; ++rr) acc2[rr] = b2v;
    for (int g = 0; g < F_DIM; ++g) {
        float w2v = W2[g * F_DIM + f];
        float4 wa = *(const float4*)&w1_s[g][0];
        float4 wb = *(const float4*)&w1_s[g][4];
        float  wc = w1_s[g][8];
        acc2[0] = fmaf(wa.x, w2v, acc2[0]);
        acc2[1] = fmaf(wa.y, w2v, acc2[1]);
        acc2[2] = fmaf(wa.z, w2v, acc2[2]);
        acc2[3] = fmaf(wa.w, w2v, acc2[3]);
        acc2[4] = fmaf(wb.x, w2v, acc2[4]);
        acc2[5] = fmaf(wb.y, w2v, acc2[5]);
        acc2[6] = fmaf(wb.z, w2v, acc2[6]);
        acc2[7] = fmaf(wb.w, w2v, acc2[7]);
        acc2[8] = fmaf(wc,   w2v, acc2[8]);
    }
#pragma unroll
    for (int rr = 0; rr <= RPB; ++rr) outs[rr][f] = ssp(acc2[rr]);
    __syncthreads();

    // pack: thread f -> pair p, row-half; emit uint2{half2(t0), half2(dt)}
    int p = f & 63;
    int rbase = (f >> 6) * (RPB / 2);
#pragma unroll
    for (int q = 0; q < RPB / 2; ++q) {
        int rr = rbase + q;
        float t00 = outs[rr][2 * p],     t01 = outs[rr][2 * p + 1];
        float n00 = outs[rr + 1][2 * p], n01 = outs[rr + 1][2 * p + 1];
        uint2 v = make_uint2(
            h22u(__halves2half2(__float2half(t00), __float2half(t01))),
            h22u(__halves2half2(__float2half(n00 - t00), __float2half(n01 - t01))));
        ptab[((size_t)l * TAB_ROWS + row0 + rr) * 64 + p] = v;
    }
}

// ---------------------------------------------------------------------------
// c[i,f] = sum_j lerp(ptab_l, d[i,j])[f] * o[j,f]
// grid: N_ATOMS x 512; thread t: pair p = t&63 (f=2p,2p+1), j-octant jc = t>>6
__global__ void __launch_bounds__(512)
conv_kernel(const uint2* __restrict__ dpk, const unsigned* __restrict__ opk,
            const uint2* __restrict__ ptab, float* __restrict__ c, int l) {
    int i  = blockIdx.x;
    int t  = threadIdx.x;
    int p  = t & 63;
    int jc = t >> 6;            // 0..7

    __shared__ uint2  ds[N_ATOMS];
    __shared__ float2 red[8][64];

    ds[t] = dpk[i * N_ATOMS + t];
    __syncthreads();

    const char* T = (const char*)(ptab + (size_t)l * TAB_ROWS * 64) + p * 8;
    float2 acc = make_float2(0.0f, 0.0f);
    int j = jc * 64;
#pragma unroll 4
    for (int jj = 0; jj < 64; ++jj, ++j) {
        uint2 e = ds[j];                         // broadcast: wave-uniform j
        __half2 fr2 = u2h2(e.y);
        uint2 tv = *(const uint2*)(T + e.x);     // {half2 t0, half2 dt}
        __half2 w2 = __hfma2(fr2, u2h2(tv.y), u2h2(tv.x));
        __half2 oh = u2h2(opk[j * 64 + p]);
        acc.x = fmaf(__half2float(__low2half(w2)),  __half2float(__low2half(oh)),  acc.x);
        acc.y = fmaf(__half2float(__high2half(w2)), __half2float(__high2half(oh)), acc.y);
    }
    red[jc][p] = acc;
    __syncthreads();
    if (jc == 0) {
        float2 s = red[0][p];
#pragma unroll
        for (int q = 1; q < 8; ++q) { s.x += red[q][p].x; s.y += red[q][p].y; }
        *(float2*)&c[i * F_DIM + 2 * p] = s;
    }
}

// ---------------------------------------------------------------------------
// h += ssp(c @ n_W1 + n_b1) @ n_W2 + n_b2; then next atom-wise (l<2) or the
// output head (l==2).  grid: N_ATOMS x 128
__global__ void node_fused(const float* __restrict__ c, const float* __restrict__ n_W1,
                           const float* __restrict__ n_b1, const float* __restrict__ n_W2,
                           const float* __restrict__ n_b2, float* __restrict__ h,
                           const float* __restrict__ aw_W, const float* __restrict__ aw_b,
                           unsigned* __restrict__ opk,
                           const float* __restrict__ oW1, const float* __restrict__ ob1,
                           const float* __restrict__ oW2, const float* __restrict__ ob2,
                           float* __restrict__ out, int l) {
    int i = blockIdx.x, f = threadIdx.x;
    __shared__ float cs[F_DIM];
    __shared__ float t1s[F_DIM];
    __shared__ float hs[F_DIM];
    cs[f] = c[i * F_DIM + f];
    __syncthreads();
    const float* W1 = n_W1 + l * F_DIM * F_DIM;
    float a = n_b1[l * F_DIM + f];
    for (int g = 0; g < F_DIM; ++g) a = fmaf(cs[g], W1[g * F_DIM + f], a);
    t1s[f] = ssp(a);
    __syncthreads();
    const float* W2 = n_W2 + l * F_DIM * F_DIM;
    float a2 = n_b2[l * F_DIM + f];
    for (int g = 0; g < F_DIM; ++g) a2 = fmaf(t1s[g], W2[g * F_DIM + f], a2);
    float hv = h[i * F_DIM + f] + a2;
    h[i * F_DIM + f] = hv;
    hs[f] = hv;
    __syncthreads();

    if (l < NLAYER - 1) {
        const float* W = aw_W + (l + 1) * F_DIM * F_DIM;
        float acc = aw_b[(l + 1) * F_DIM + f];
        for (int g = 0; g < F_DIM; ++g) acc = fmaf(hs[g], W[g * F_DIM + f], acc);
        t1s[f] = acc;      // reuse as staging
        __syncthreads();
        if (f < F_DIM / 2)
            opk[i * 64 + f] = h22u(__halves2half2(__float2half(t1s[2 * f]),
                                                  __float2half(t1s[2 * f + 1])));
    } else {
        float val = 0.0f;
        if (f < 32) {
            float ah = ob1[f];
            for (int g = 0; g < F_DIM; ++g) ah = fmaf(hs[g], oW1[g * 32 + f], ah);
            val = ssp(ah) * oW2[f];
        }
#pragma unroll
        for (int off = 16; off > 0; off >>= 1) val += __shfl_xor(val, off, 64);
        if (f == 0) out[i] = val + ob2[0];
    }
}

// ---------------------------------------------------------------------------
extern "C" void kernel_launch(void* const* d_in, const int* in_sizes, int n_in,
                              void* d_out, int out_size, void* d_ws, size_t ws_size,
                              hipStream_t stream) {
    const int*   x     = (const int*)  d_in[0];
    const float* r     = (const float*)d_in[1];
    const float* emb   = (const float*)d_in[2];
    const float* aw_W  = (const float*)d_in[3];
    const float* aw_b  = (const float*)d_in[4];
    const float* cf_W1 = (const float*)d_in[5];
    const float* cf_b1 = (const float*)d_in[6];
    const float* cf_W2 = (const float*)d_in[7];
    const float* cf_b2 = (const float*)d_in[8];
    const float* n_W1  = (const float*)d_in[9];
    const float* n_b1  = (const float*)d_in[10];
    const float* n_W2  = (const float*)d_in[11];
    const float* n_b2  = (const float*)d_in[12];
    const float* oW1   = (const float*)d_in[13];
    const float* ob1   = (const float*)d_in[14];
    const float* oW2   = (const float*)d_in[15];
    const float* ob2   = (const float*)d_in[16];
    float* out = (float*)d_out;

    char* ws = (char*)d_ws;
    uint2*    dpk  = (uint2*)ws;    ws += (size_t)N_ATOMS * N_ATOMS * 8;          // 2 MB
    float*    h    = (float*)ws;    ws += (size_t)N_ATOMS * F_DIM * 4;            // 256 KB
    unsigned* opk  = (unsigned*)ws; ws += (size_t)N_ATOMS * (F_DIM / 2) * 4;      // 128 KB
    float*    c    = (float*)ws;    ws += (size_t)N_ATOMS * F_DIM * 4;            // 256 KB
    uint2*    ptab = (uint2*)ws;                                                  // 2.7 MB

    prep_kernel<<<N_ATOMS, 256, 0, stream>>>(x, r, emb, aw_W, aw_b, dpk, h, opk);
    build_tables<<<dim3(TAB_ROWS / RPB, NLAYER), 128, 0, stream>>>(cf_W1, cf_b1, cf_W2, cf_b2, ptab);
    for (int l = 0; l < NLAYER; ++l) {
        conv_kernel<<<N_ATOMS, 512, 0, stream>>>(dpk, opk, ptab, c, l);
        node_fused<<<N_ATOMS, 128, 0, stream>>>(c, n_W1, n_b1, n_W2, n_b2, h,
                                                aw_W, aw_b, opk, oW1, ob1, oW2, ob2, out, l);
    }
}

// Round 4
// 168.953 us; speedup vs baseline: 1.3089x; 1.0367x over previous
//
#include <hip/hip_runtime.h>
#include <hip/hip_fp16.h>
#include <math.h>

#define N_ATOMS 512
#define F_DIM   128
#define K_RBF   301
#define NLAYER  3
#define GAMMA_C 10.0f
#define LOG2_C  0.6931471805599453f

// Filter lookup table: w_l(d) sampled at step TAB_H; max d = 10*sqrt(3) = 17.32
#define TAB_H     0.01f
#define TAB_INVH  100.0f
#define TAB_ROWS  1768          // 221 * 8, covers up to 17.67
#define RPB       8             // table rows emitted per task (computes RPB+1)
#define NGROUPS   (TAB_ROWS / RPB)          // 221
#define NTASKS    (NGROUPS * NLAYER)        // 663 (row-group, layer) tasks
#define NBBLK     ((NTASKS + 1) / 2)        // 332 build blocks, 2 tasks each
#define ROW_BYTES 512           // 64 f-pairs * 8 B (uint2 per pair)

__device__ __forceinline__ float ssp(float x) {
    float ax = fabsf(x);
    return fmaxf(x, 0.0f) + log1pf(expf(-ax)) - LOG2_C;
}
__device__ __forceinline__ __half2 u2h2(unsigned u) {
    union { unsigned u; __half2 h; } c; c.u = u; return c.h;
}
__device__ __forceinline__ unsigned h22u(__half2 h) {
    union { unsigned u; __half2 h; } c; c.h = h; return c.u;
}

// ---------------------------------------------------------------------------
// Fused prep + table build.  grid: (512 + 332) x 256
//   blocks [0,512):   dpk[i,j] = (row byte offset, fr half2); h = emb[x];
//                     opk0 = half2(h @ aw_W[0] + aw_b[0])
//   blocks [512,844): 2 tasks/block; task = (row-group, layer):
//                     ptab[l,row,p] = uint2{half2(t0), half2(t1-t0)}
__global__ void __launch_bounds__(256)
prep_build(const int* __restrict__ x, const float* __restrict__ r,
           const float* __restrict__ emb,
           const float* __restrict__ aw_W, const float* __restrict__ aw_b,
           const float* __restrict__ cf_W1, const float* __restrict__ cf_b1,
           const float* __restrict__ cf_W2, const float* __restrict__ cf_b2,
           uint2* __restrict__ dpk, float* __restrict__ h,
           unsigned* __restrict__ opk, uint2* __restrict__ ptab) {
    __shared__ float hs[F_DIM];
    __shared__ float os[F_DIM];
    __shared__ float e_s[2][RPB + 1][34];
    __shared__ float w1_s[2][F_DIM][12];
    __shared__ float outs[2][RPB + 1][F_DIM];

    if (blockIdx.x < N_ATOMS) {
        // ---- prep path ----
        int i = blockIdx.x;
        int t = threadIdx.x;
        float rx = r[i * 3 + 0], ry = r[i * 3 + 1], rz = r[i * 3 + 2];
        if (t < F_DIM) {
            float hv = emb[x[i] * F_DIM + t];
            h[i * F_DIM + t] = hv;
            hs[t] = hv;
        }
        for (int j = t; j < N_ATOMS; j += 256) {
            float dx = rx - r[j * 3 + 0];
            float dy = ry - r[j * 3 + 1];
            float dz = rz - r[j * 3 + 2];
            float d  = sqrtf(dx * dx + dy * dy + dz * dz);
            float xb = d * TAB_INVH;
            int   b  = ::min((int)xb, TAB_ROWS - 2);
            float fr = xb - (float)b;
            __half fh = __float2half(fr);
            dpk[i * N_ATOMS + j] = make_uint2((unsigned)b * ROW_BYTES,
                                              h22u(__halves2half2(fh, fh)));
        }
        __syncthreads();
        if (t < F_DIM) {
            float acc = aw_b[t];
            for (int g = 0; g < F_DIM; ++g) acc = fmaf(hs[g], aw_W[g * F_DIM + t], acc);
            os[t] = acc;
        }
        __syncthreads();
        if (t < F_DIM / 2)
            opk[i * 64 + t] = h22u(__halves2half2(__float2half(os[2 * t]),
                                                  __float2half(os[2 * t + 1])));
        return;
    }

    // ---- build path: 2 tasks per block ----
    int u = threadIdx.x >> 7;                    // unit 0/1
    int f = threadIdx.x & 127;
    int task = (blockIdx.x - N_ATOMS) * 2 + u;
    bool valid = task < NTASKS;
    task = ::min(task, NTASKS - 1);
    int l    = task / NGROUPS;
    int row0 = (task % NGROUPS) * RPB;

    float dlo = row0 * TAB_H;
    float dhi = (row0 + RPB) * TAB_H;
    // Gaussian window: exp(-10*1.45^2) ~ 7.6e-10 truncation
    int k0 = ::max(0, (int)ceilf((dlo - 1.45f) * 10.0f));
    int k1 = ::min(K_RBF - 1, (int)floorf((dhi + 1.45f) * 10.0f));
    int kw = k1 - k0 + 1;   // <= ~31

    for (int idx = f; idx < (RPB + 1) * kw; idx += F_DIM) {
        int rr = idx / kw, kk = idx % kw;
        float dv = (row0 + rr) * TAB_H;
        float tt = dv - 0.1f * (float)(k0 + kk);
        e_s[u][rr][kk] = expf(-GAMMA_C * tt * tt);
    }
    __syncthreads();

    const float* W1 = cf_W1 + l * K_RBF * F_DIM;
    float b1v = cf_b1[l * F_DIM + f];
    float acc[RPB + 1];
#pragma unroll
    for (int rr = 0; rr <= RPB; ++rr) acc[rr] = b1v;
    for (int kk = 0; kk < kw; ++kk) {
        float w1v = W1[(k0 + kk) * F_DIM + f];
#pragma unroll
        for (int rr = 0; rr <= RPB; ++rr) acc[rr] = fmaf(e_s[u][rr][kk], w1v, acc[rr]);
    }
#pragma unroll
    for (int rr = 0; rr <= RPB; ++rr) w1_s[u][f][rr] = ssp(acc[rr]);
    __syncthreads();

    const float* W2 = cf_W2 + l * F_DIM * F_DIM;
    float b2v = cf_b2[l * F_DIM + f];
    float acc2[RPB + 1];
#pragma unroll
    for (int rr = 0; rr <= RPB; ++rr) acc2[rr] = b2v;
    for (int g = 0; g < F_DIM; ++g) {
        float w2v = W2[g * F_DIM + f];
        float4 wa = *(const float4*)&w1_s[u][g][0];
        float4 wb = *(const float4*)&w1_s[u][g][4];
        float  wc = w1_s[u][g][8];
        acc2[0] = fmaf(wa.x, w2v, acc2[0]);
        acc2[1] = fmaf(wa.y, w2v, acc2[1]);
        acc2[2] = fmaf(wa.z, w2v, acc2[2]);
        acc2[3] = fmaf(wa.w, w2v, acc2[3]);
        acc2[4] = fmaf(wb.x, w2v, acc2[4]);
        acc2[5] = fmaf(wb.y, w2v, acc2[5]);
        acc2[6] = fmaf(wb.z, w2v, acc2[6]);
        acc2[7] = fmaf(wb.w, w2v, acc2[7]);
        acc2[8] = fmaf(wc,   w2v, acc2[8]);
    }
#pragma unroll
    for (int rr = 0; rr <= RPB; ++rr) outs[u][rr][f] = ssp(acc2[rr]);
    __syncthreads();

    if (valid) {
        // pack: thread f -> pair p, row-half; emit uint2{half2(t0), half2(dt)}
        int p = f & 63;
        int rbase = (f >> 6) * (RPB / 2);
#pragma unroll
        for (int q = 0; q < RPB / 2; ++q) {
            int rr = rbase + q;
            float t00 = outs[u][rr][2 * p],     t01 = outs[u][rr][2 * p + 1];
            float n00 = outs[u][rr + 1][2 * p], n01 = outs[u][rr + 1][2 * p + 1];
            uint2 v = make_uint2(
                h22u(__halves2half2(__float2half(t00), __float2half(t01))),
                h22u(__halves2half2(__float2half(n00 - t00), __float2half(n01 - t01))));
            ptab[((size_t)l * TAB_ROWS + row0 + rr) * 64 + p] = v;
        }
    }
}

// ---------------------------------------------------------------------------
// Fused conv + node (+ next atomwise / output head).  grid: N_ATOMS x 512
//   conv:  c[f] = sum_j lerp(ptab_l, d[i,j])[f] * o_in[j,f]   (c kept in LDS)
//   node:  h += ssp(c @ n_W1 + n_b1) @ n_W2 + n_b2
//   then:  o_out = half2(h @ aw_W[l+1] + aw_b[l+1])   (l<2)
//     or:  out[i] = ssp(h @ oW1 + ob1) @ oW2 + ob2    (l==2)
// o double-buffered across launches: conv reads opk_in, tail writes opk_out.
__global__ void __launch_bounds__(512)
convnode_kernel(const uint2* __restrict__ dpk, const unsigned* __restrict__ opk_in,
                const uint2* __restrict__ ptab,
                const float* __restrict__ n_W1, const float* __restrict__ n_b1,
                const float* __restrict__ n_W2, const float* __restrict__ n_b2,
                float* __restrict__ h,
                const float* __restrict__ aw_W, const float* __restrict__ aw_b,
                unsigned* __restrict__ opk_out,
                const float* __restrict__ oW1, const float* __restrict__ ob1,
                const float* __restrict__ oW2, const float* __restrict__ ob2,
                float* __restrict__ out, int l) {
    int i  = blockIdx.x;
    int t  = threadIdx.x;
    int p  = t & 63;
    int jc = t >> 6;            // 0..7

    __shared__ uint2  ds[N_ATOMS];
    __shared__ float2 red[8][64];
    __shared__ float  cs[F_DIM];
    __shared__ float  t1s[F_DIM];
    __shared__ float  hs[F_DIM];

    ds[t] = dpk[i * N_ATOMS + t];
    if (t < F_DIM) hs[t] = h[i * F_DIM + t];
    __syncthreads();

    // ---- conv ----
    const char* T = (const char*)(ptab + (size_t)l * TAB_ROWS * 64) + p * 8;
    float2 acc = make_float2(0.0f, 0.0f);
    int j = jc * 64;
#pragma unroll 4
    for (int jj = 0; jj < 64; ++jj, ++j) {
        uint2 e = ds[j];                         // broadcast: wave-uniform j
        uint2 tv = *(const uint2*)(T + e.x);     // {half2 t0, half2 dt}
        __half2 w2 = __hfma2(u2h2(e.y), u2h2(tv.y), u2h2(tv.x));
        __half2 oh = u2h2(opk_in[j * 64 + p]);
        acc.x = fmaf(__half2float(__low2half(w2)),  __half2float(__low2half(oh)),  acc.x);
        acc.y = fmaf(__half2float(__high2half(w2)), __half2float(__high2half(oh)), acc.y);
    }
    red[jc][p] = acc;
    __syncthreads();
    if (jc == 0) {
        float2 s = red[0][p];
#pragma unroll
        for (int q = 1; q < 8; ++q) { s.x += red[q][p].x; s.y += red[q][p].y; }
        *(float2*)&cs[2 * p] = s;
    }
    __syncthreads();

    // ---- node MLP ----
    if (t < F_DIM) {
        const float* W1 = n_W1 + l * F_DIM * F_DIM;
        float a = n_b1[l * F_DIM + t];
        for (int g = 0; g < F_DIM; ++g) a = fmaf(cs[g], W1[g * F_DIM + t], a);
        t1s[t] = ssp(a);
    }
    __syncthreads();
    if (t < F_DIM) {
        const float* W2 = n_W2 + l * F_DIM * F_DIM;
        float a2 = n_b2[l * F_DIM + t];
        for (int g = 0; g < F_DIM; ++g) a2 = fmaf(t1s[g], W2[g * F_DIM + t], a2);
        float hv = hs[t] + a2;               // own element only: safe in-place
        h[i * F_DIM + t] = hv;
        hs[t] = hv;
    }
    __syncthreads();

    if (l < NLAYER - 1) {
        // next layer's atom-wise linear, packed to half2
        if (t < F_DIM) {
            const float* W = aw_W + (l + 1) * F_DIM * F_DIM;
            float a = aw_b[(l + 1) * F_DIM + t];
            for (int g = 0; g < F_DIM; ++g) a = fmaf(hs[g], W[g * F_DIM + t], a);
            t1s[t] = a;
        }
        __syncthreads();
        if (t < F_DIM / 2)
            opk_out[i * 64 + t] = h22u(__halves2half2(__float2half(t1s[2 * t]),
                                                      __float2half(t1s[2 * t + 1])));
    } else {
        // output head
        float val = 0.0f;
        if (t < 32) {
            float ah = ob1[t];
            for (int g = 0; g < F_DIM; ++g) ah = fmaf(hs[g], oW1[g * 32 + t], ah);
            val = ssp(ah) * oW2[t];
        }
#pragma unroll
        for (int off = 16; off > 0; off >>= 1) val += __shfl_xor(val, off, 64);
        if (t == 0) out[i] = val + ob2[0];
    }
}

// ---------------------------------------------------------------------------
extern "C" void kernel_launch(void* const* d_in, const int* in_sizes, int n_in,
                              void* d_out, int out_size, void* d_ws, size_t ws_size,
                              hipStream_t stream) {
    const int*   x     = (const int*)  d_in[0];
    const float* r     = (const float*)d_in[1];
    const float* emb   = (const float*)d_in[2];
    const float* aw_W  = (const float*)d_in[3];
    const float* aw_b  = (const float*)d_in[4];
    const float* cf_W1 = (const float*)d_in[5];
    const float* cf_b1 = (const float*)d_in[6];
    const float* cf_W2 = (const float*)d_in[7];
    const float* cf_b2 = (const float*)d_in[8];
    const float* n_W1  = (const float*)d_in[9];
    const float* n_b1  = (const float*)d_in[10];
    const float* n_W2  = (const float*)d_in[11];
    const float* n_b2  = (const float*)d_in[12];
    const float* oW1   = (const float*)d_in[13];
    const float* ob1   = (const float*)d_in[14];
    const float* oW2   = (const float*)d_in[15];
    const float* ob2   = (const float*)d_in[16];
    float* out = (float*)d_out;

    char* ws = (char*)d_ws;
    uint2*    dpk  = (uint2*)ws;    ws += (size_t)N_ATOMS * N_ATOMS * 8;      // 2 MB
    float*    h    = (float*)ws;    ws += (size_t)N_ATOMS * F_DIM * 4;        // 256 KB
    unsigned* opkA = (unsigned*)ws; ws += (size_t)N_ATOMS * (F_DIM / 2) * 4;  // 128 KB
    unsigned* opkB = (unsigned*)ws; ws += (size_t)N_ATOMS * (F_DIM / 2) * 4;  // 128 KB
    uint2*    ptab = (uint2*)ws;                                              // 2.7 MB

    prep_build<<<N_ATOMS + NBBLK, 256, 0, stream>>>(
        x, r, emb, aw_W, aw_b, cf_W1, cf_b1, cf_W2, cf_b2, dpk, h, opkA, ptab);
    for (int l = 0; l < NLAYER; ++l) {
        unsigned* oin  = (l & 1) ? opkB : opkA;
        unsigned* oout = (l & 1) ? opkA : opkB;
        convnode_kernel<<<N_ATOMS, 512, 0, stream>>>(
            dpk, oin, ptab, n_W1, n_b1, n_W2, n_b2, h,
            aw_W, aw_b, oout, oW1, ob1, oW2, ob2, out, l);
    }
}